// Round 16
// baseline (692.718 us; speedup 1.0000x reference)
//
#include <hip/hip_runtime.h>
#include <hip/hip_bf16.h>
#include <math.h>

#define NN 768
#define FF 128
#define VV 64
#define RH 16
#define SPLITK 32
#define SEND_PER_KC 24          // 768 / SPLITK
#define NITER 3                 // SEND_PER_KC / 8 senders per iter
#define KSTEPS 384              // 12288 / 32
#define NT_S 8                  // scalar n-tiles (128/16)
#define NT_V 16                 // vector n-tiles (256/16)
#define MB_N 24                 // M-blocks (768/32)
#define GRID 768
#define PREP_TOT (KSTEPS * 24 * 64)   // 589824
#define FLAG_STRIDE 32                 // 128 B per block flag

typedef __attribute__((ext_vector_type(8))) short bf16x8_t;
typedef __attribute__((ext_vector_type(4))) float f32x4;

__device__ __forceinline__ float silu_f(float a) {
  return a * __builtin_amdgcn_rcpf(1.0f + __expf(-a));
}

__device__ __forceinline__ short f2bf(float f) {
  __hip_bfloat16 h = __float2bfloat16(f);  // RNE; pairs into v_cvt_pk_bf16_f32
  return __builtin_bit_cast(short, h);
}

__device__ __forceinline__ float bf2f(unsigned short v) {
  return __builtin_bit_cast(float, (unsigned)v << 16);
}

// Contention-free grid barrier:
//  - every block STORES phase to its own 128B-strided flag (no RMW, no
//    ownership contention)
//  - block 0's 256 threads scan the 767 flags in parallel (read-only),
//    then publish one release word
//  - other blocks spin READ-ONLY on the release word (shared, no
//    exclusivity transfer -> no serialization)
// flags/release zeroed once per launch by a captured hipMemsetAsync.
__device__ __forceinline__ void gbar(unsigned* flags, unsigned* release,
                                     unsigned phase) {
  __threadfence();
  __syncthreads();
  const int b = blockIdx.x, tid = threadIdx.x;
  if (b == 0) {
    for (int i = 1 + tid; i < GRID; i += 256) {
      while (__hip_atomic_load(&flags[i * FLAG_STRIDE], __ATOMIC_ACQUIRE,
                               __HIP_MEMORY_SCOPE_AGENT) < phase)
        __builtin_amdgcn_s_sleep(1);
    }
    __syncthreads();
    if (tid == 0)
      __hip_atomic_store(release, phase, __ATOMIC_RELEASE,
                         __HIP_MEMORY_SCOPE_AGENT);
  } else {
    if (tid == 0) {
      __hip_atomic_store(&flags[b * FLAG_STRIDE], phase, __ATOMIC_RELEASE,
                         __HIP_MEMORY_SCOPE_AGENT);
      while (__hip_atomic_load(release, __ATOMIC_ACQUIRE,
                               __HIP_MEMORY_SCOPE_AGENT) < phase)
        __builtin_amdgcn_s_sleep(2);
    }
    __syncthreads();
  }
  __threadfence();
}

// ---------------------------------------------------------------------------
// MEGA kernel: [layer0] gbar [prep] gbar [edge GEMM] gbar [final].
// grid = 768 = 3 blocks/CU exactly; launch_bounds(256,3) + 38.9 KB LDS
// guarantee co-residency (proven by R15 completing). Phase bodies = R14/R15
// verified code.
// ---------------------------------------------------------------------------
__global__ __launch_bounds__(256, 3) void mega_kernel(
    const float* __restrict__ x,
    const float* __restrict__ embed,
    const float* __restrict__ Wr1,     // [2][16]
    const float* __restrict__ Wr2s,    // [2][16][128]
    const float* __restrict__ Wr2v,    // [2][16][64]
    const float* __restrict__ Wsv,     // [2][128][64]
    const float* __restrict__ Wss,     // [2][128][128]
    const float* __restrict__ Wvs,     // [2][64][128]
    const float* __restrict__ Wvv,     // [2][64][64]
    const float* __restrict__ Wro_s1,
    const float* __restrict__ Wro_s2,
    const float* __restrict__ Wro_v1,
    const float* __restrict__ Wro_v2,
    float* hs, float* hsv, float* hv,
    unsigned short* Ps, unsigned short* Pv,
    unsigned short* Bs, unsigned short* Bv,
    unsigned* flags, unsigned* release,
    float* out)
{
  __shared__ float S[9728];   // 38.9 KB, aliased per phase
  const int tid = threadIdx.x;
  const int b   = blockIdx.x;

  //========================= PHASE 1: layer0 ================================
  {
    float* accT  = S;            // 256*33 = 8448
    float* red8  = S + 8448;     // 8*32 = 256
    float* fin   = S + 8704;     // 64
    float* cvs   = S + 8768;     // 64
    float* as_l  = S + 8832;     // 128
    float* av_l  = S + 8960;     // 192
    float* inv_l = S + 9152;     // 64
    float* hsn   = S + 9216;     // 128
    float* redn  = S + 9344;     // 256
    const int r = b;
    const float* Wsv1 = Wsv + FF * VV;

    if (tid < 64) {
      float a = 0.f;
      #pragma unroll 8
      for (int f = 0; f < FF; ++f) a += embed[f] * Wsv[f * VV + tid];
      cvs[tid] = a;
    }

    float wr1[RH];
    #pragma unroll
    for (int hh = 0; hh < RH; ++hh) wr1[hh] = Wr1[hh];

    const float xr0 = x[r * 3 + 0], xr1 = x[r * 3 + 1], xr2 = x[r * 3 + 2];

    float acc[64];
    #pragma unroll
    for (int i = 0; i < 64; ++i) acc[i] = 0.f;

    #pragma unroll
    for (int ss = 0; ss < 3; ++ss) {
      const int s = tid + ss * 256;
      const float vx = x[s * 3 + 0] - xr0;
      const float vy = x[s * 3 + 1] - xr1;
      const float vz = x[s * 3 + 2] - xr2;
      const float d  = __builtin_amdgcn_sqrtf(vx * vx + vy * vy + vz * vz);
      const float iv = __builtin_amdgcn_rcpf(d + 1e-8f);
      const float ux = vx * iv, uy = vy * iv, uz = vz * iv;
      #pragma unroll
      for (int h = 0; h < RH; ++h) {
        const float rf = silu_f(d * wr1[h]);
        acc[h * 4 + 0] += rf;
        acc[h * 4 + 1] += rf * ux;
        acc[h * 4 + 2] += rf * uy;
        acc[h * 4 + 3] += rf * uz;
      }
    }

    // transpose-reduce, two 33-pitch rounds
    #pragma unroll
    for (int i = 0; i < 32; ++i) accT[tid * 33 + i] = acc[i];
    __syncthreads();
    {
      const int j2 = tid & 31, q2 = tid >> 5;
      float a0 = 0.f, a1 = 0.f;
      #pragma unroll 8
      for (int rr = 0; rr < 32; rr += 2) {
        a0 += accT[(q2 * 32 + rr) * 33 + j2];
        a1 += accT[(q2 * 32 + rr + 1) * 33 + j2];
      }
      red8[q2 * 32 + j2] = a0 + a1;
    }
    __syncthreads();
    if (tid < 32) {
      float a = 0.f;
      #pragma unroll
      for (int g = 0; g < 8; ++g) a += red8[g * 32 + tid];
      fin[tid] = a;
    }
    __syncthreads();
    #pragma unroll
    for (int i = 0; i < 32; ++i) accT[tid * 33 + i] = acc[32 + i];
    __syncthreads();
    {
      const int j2 = tid & 31, q2 = tid >> 5;
      float a0 = 0.f, a1 = 0.f;
      #pragma unroll 8
      for (int rr = 0; rr < 32; rr += 2) {
        a0 += accT[(q2 * 32 + rr) * 33 + j2];
        a1 += accT[(q2 * 32 + rr + 1) * 33 + j2];
      }
      red8[q2 * 32 + j2] = a0 + a1;
    }
    __syncthreads();
    if (tid < 32) {
      float a = 0.f;
      #pragma unroll
      for (int g = 0; g < 8; ++g) a += red8[g * 32 + tid];
      fin[32 + tid] = a;
    }
    __syncthreads();

    if (tid < FF) {
      float a = 0.f;
      #pragma unroll
      for (int hh = 0; hh < RH; ++hh) a += fin[hh * 4] * Wr2s[hh * FF + tid];
      as_l[tid] = a * embed[tid] * (1.0f / 64.0f);
    }
    if (tid < 192) {
      const int v = tid / 3, d = tid - v * 3;
      float a = 0.f;
      #pragma unroll
      for (int hh = 0; hh < RH; ++hh) a += fin[hh * 4 + 1 + d] * Wr2v[hh * VV + v];
      av_l[tid] = a * cvs[v] * (1.0f / 64.0f);
    }
    __syncthreads();

    if (tid < VV) {
      const float a0 = av_l[tid * 3 + 0], a1 = av_l[tid * 3 + 1], a2 = av_l[tid * 3 + 2];
      inv_l[tid] = a0 * a0 + a1 * a1 + a2 * a2;
    }
    __syncthreads();

    {
      const int f = tid & 127, part = tid >> 7;
      float a = 0.f;
      const float* wp = Wss + (part * 64) * FF + f;
      #pragma unroll 8
      for (int kk = 0; kk < 64; ++kk) a += as_l[part * 64 + kk] * wp[kk * FF];
      const float* vp = Wvs + (part * 32) * FF + f;
      #pragma unroll 8
      for (int vv = 0; vv < 32; ++vv) a += inv_l[part * 32 + vv] * vp[vv * FF];
      redn[part * 128 + f] = a;
    }
    __syncthreads();

    if (tid < FF) {
      const float hnew = silu_f(embed[tid] + redn[tid] + redn[128 + tid]);
      hs[(size_t)r * FF + tid] = hnew;
      hsn[tid] = hnew;
    }
    if (tid < 192) {
      const int w = tid / 3, d = tid - w * 3;
      float a = 0.f;
      #pragma unroll 8
      for (int v = 0; v < VV; ++v) a += av_l[v * 3 + d] * Wvv[v * VV + w];
      hv[(size_t)r * 192 + tid] = a;
    }
    __syncthreads();

    {
      const int v = tid & 63, part = tid >> 6;
      float a = 0.f;
      const float* wp = Wsv1 + (part * 32) * VV + v;
      #pragma unroll 8
      for (int f = 0; f < 32; ++f) a += hsn[part * 32 + f] * wp[f * VV];
      redn[tid] = a;
    }
    __syncthreads();
    if (tid < VV)
      hsv[(size_t)r * VV + tid] = redn[tid] + redn[64 + tid] + redn[128 + tid] + redn[192 + tid];
  }
  gbar(flags, release, 1u);

  //========================= PHASE 2: prep (grid-strided) ==================
  {
    const float* W2s = Wr2s + RH * FF;
    const float* W2v = Wr2v + RH * VV;
    for (int gid = b * 256 + tid; gid < PREP_TOT; gid += GRID * 256) {
      const int lane  = gid & 63;
      const int tmp   = gid >> 6;
      const int ntile = tmp % 24;
      const int kstep = tmp / 24;
      const int qq = lane >> 4;
      const int s  = kstep * 2 + (qq >> 1);
      const int hb = (qq & 1) * 8;

      bf16x8_t o;
      if (ntile < NT_S) {
        const int f = ntile * 16 + (lane & 15);
        const float hf = hs[s * FF + f] * 0.015625f;
        #pragma unroll
        for (int e = 0; e < 8; ++e)
          o[e] = f2bf(hf * W2s[(hb + e) * FF + f]);
        *(bf16x8_t*)&Bs[((size_t)(kstep * NT_S + ntile) * 64 + lane) * 8] = o;
      } else {
        const int nt2 = ntile - NT_S;
        const int n   = nt2 * 16 + (lane & 15);
        int v; float scale;
        if (n < 192) { const int dd = n >> 6; v = n & 63;
                       scale = x[s * 3 + dd] * hsv[s * VV + v] * 0.015625f; }
        else         { v = n - 192; scale = hsv[s * VV + v] * 0.015625f; }
        #pragma unroll
        for (int e = 0; e < 8; ++e)
          o[e] = f2bf(scale * W2v[(hb + e) * VV + v]);
        *(bf16x8_t*)&Bv[((size_t)(kstep * NT_V + nt2) * 64 + lane) * 8] = o;
      }
    }
  }
  gbar(flags, release, 2u);

  //========================= PHASE 3: edge GEMM (SPLITK=32) ================
  {
    unsigned short* A_lds = (unsigned short*)S;            // 8 KB
    unsigned short* G_lds = (unsigned short*)(S + 2048);   // 8 KB

    // XCD swizzle: 768 = 8 * 96; xcd owns kc in [4*xcd, 4*xcd+4)
    const int wg = ((b & 7) * 96) + (b >> 3);
    const int kc = wg / MB_N;        // 0..31
    const int mb = wg - kc * MB_N;   // 0..23

    const int lane = tid & 63;
    const int w    = tid >> 6;
    const float* Wr1e = Wr1 + RH;

    float wr1[RH];
    #pragma unroll
    for (int h = 0; h < RH; ++h) wr1[h] = Wr1e[h];

    const int r_local = tid & 31;
    const int s_ii    = tid >> 5;
    const int r = mb * 32 + r_local;
    const int mt_w  = r_local >> 4;
    const int ks_w  = s_ii >> 1;
    const int lane0 = (r_local & 15) + ((s_ii & 1) << 5);

    const float xr0 = x[r * 3 + 0], xr1 = x[r * 3 + 1], xr2 = x[r * 3 + 2];
    float sx[NITER], sy[NITER], sz[NITER];
    #pragma unroll
    for (int it = 0; it < NITER; ++it) {
      const int s = kc * SEND_PER_KC + it * 8 + s_ii;
      sx[it] = x[s * 3 + 0]; sy[it] = x[s * 3 + 1]; sz[it] = x[s * 3 + 2];
    }

    f32x4 accS[4], accV[8];
    #pragma unroll
    for (int i = 0; i < 4; ++i) accS[i] = (f32x4){0.f, 0.f, 0.f, 0.f};
    #pragma unroll
    for (int i = 0; i < 8; ++i) accV[i] = (f32x4){0.f, 0.f, 0.f, 0.f};

    for (int it = 0; it < NITER; ++it) {
      {
        const float vx = sx[it] - xr0;
        const float vy = sy[it] - xr1;
        const float vz = sz[it] - xr2;
        const float dd = __builtin_amdgcn_sqrtf(vx * vx + vy * vy + vz * vz);
        const float iv = __builtin_amdgcn_rcpf(dd + 1e-8f);
        float sv[RH];
        #pragma unroll
        for (int h = 0; h < RH; ++h) sv[h] = silu_f(dd * wr1[h]);
        bf16x8_t o0, o1, g0, g1;
        #pragma unroll
        for (int h = 0; h < 8; ++h) {
          o0[h] = f2bf(sv[h]);
          o1[h] = f2bf(sv[h + 8]);
          g0[h] = f2bf(sv[h] * iv);
          g1[h] = f2bf(sv[h + 8] * iv);
        }
        const int off0 = ((ks_w * 2 + mt_w) * 64 + lane0) * 8;
        *(bf16x8_t*)&A_lds[off0]       = o0;
        *(bf16x8_t*)&A_lds[off0 + 128] = o1;
        *(bf16x8_t*)&G_lds[off0]       = g0;
        *(bf16x8_t*)&G_lds[off0 + 128] = g1;
      }
      __syncthreads();

      const int kgb = kc * (SEND_PER_KC / 2) + it * 4;
      #pragma unroll
      for (int ks = 0; ks < 4; ++ks) {
        const bf16x8_t b0 =
            *(const bf16x8_t*)&Bs[((size_t)((kgb + ks) * NT_S + 2 * w) * 64 + lane) * 8];
        const bf16x8_t b1 =
            *(const bf16x8_t*)&Bs[((size_t)((kgb + ks) * NT_S + 2 * w + 1) * 64 + lane) * 8];
        bf16x8_t bv[4];
        #pragma unroll
        for (int j = 0; j < 4; ++j)
          bv[j] = *(const bf16x8_t*)&Bv[((size_t)((kgb + ks) * NT_V + 4 * w + j) * 64 + lane) * 8];
        #pragma unroll
        for (int mt = 0; mt < 2; ++mt) {
          const int aoff = ((ks * 2 + mt) * 64 + lane) * 8;
          const bf16x8_t a  = *(const bf16x8_t*)&A_lds[aoff];
          const bf16x8_t ag = *(const bf16x8_t*)&G_lds[aoff];
          accS[mt * 2 + 0] = __builtin_amdgcn_mfma_f32_16x16x32_bf16(a, b0, accS[mt * 2 + 0], 0, 0, 0);
          accS[mt * 2 + 1] = __builtin_amdgcn_mfma_f32_16x16x32_bf16(a, b1, accS[mt * 2 + 1], 0, 0, 0);
          #pragma unroll
          for (int j = 0; j < 4; ++j)
            accV[mt * 4 + j] = __builtin_amdgcn_mfma_f32_16x16x32_bf16(ag, bv[j], accV[mt * 4 + j], 0, 0, 0);
        }
      }
      __syncthreads();
    }

    const int rowq = (lane >> 4) << 2;
    #pragma unroll
    for (int j = 0; j < 2; ++j) {
      const int col = (2 * w + j) * 16 + (lane & 15);
      #pragma unroll
      for (int mt = 0; mt < 2; ++mt) {
        #pragma unroll
        for (int reg = 0; reg < 4; ++reg) {
          const int row = mb * 32 + mt * 16 + rowq + reg;
          Ps[((size_t)kc * NN + row) * FF + col] =
              (unsigned short)f2bf(accS[mt * 2 + j][reg]);
        }
      }
    }
    #pragma unroll
    for (int j = 0; j < 4; ++j) {
      const int col = (4 * w + j) * 16 + (lane & 15);
      #pragma unroll
      for (int mt = 0; mt < 2; ++mt) {
        #pragma unroll
        for (int reg = 0; reg < 4; ++reg) {
          const int row = mb * 32 + mt * 16 + rowq + reg;
          Pv[((size_t)kc * NN + row) * 256 + col] =
              (unsigned short)f2bf(accV[mt * 4 + j][reg]);
        }
      }
    }
  }
  gbar(flags, release, 3u);

  //========================= PHASE 4: final (256-thread) ===================
  {
    float* as_l  = S;            // 128
    float* pvs_l = S + 128;      // 256
    float* av_l  = S + 384;      // 192
    float* inv_l = S + 576;      // 64
    float* hsn   = S + 640;      // 128
    float* hv_l  = S + 768;      // 192
    float* red   = S + 960;      // 256
    float* t1    = S + 1216;     // 128
    float* tv1   = S + 1344;     // 192
    const int n = b;
    const float* Wss1 = Wss + FF * FF;
    const float* Wvs1 = Wvs + VV * FF;
    const float* Wvv1 = Wvv + VV * VV;

    // fused splitK reduce (bf16 loads)
    {
      float a = 0.f;
      #pragma unroll
      for (int kc = 0; kc < SPLITK; ++kc)
        a += bf2f(Pv[((size_t)kc * NN + n) * 256 + tid]);
      pvs_l[tid] = a;
      if (tid < FF) {
        float c = 0.f;
        #pragma unroll
        for (int kc = 0; kc < SPLITK; ++kc)
          c += bf2f(Ps[((size_t)kc * NN + n) * FF + tid]);
        as_l[tid] = c;
      }
    }
    __syncthreads();

    if (tid < VV) {
      const float base = pvs_l[192 + tid];
      const float a0 = pvs_l[tid]       - x[n * 3 + 0] * base;
      const float a1 = pvs_l[64 + tid]  - x[n * 3 + 1] * base;
      const float a2 = pvs_l[128 + tid] - x[n * 3 + 2] * base;
      av_l[tid * 3 + 0] = a0; av_l[tid * 3 + 1] = a1; av_l[tid * 3 + 2] = a2;
      inv_l[tid] = a0 * a0 + a1 * a1 + a2 * a2;
    }
    __syncthreads();

    // hs GEMV: 2-way K split
    {
      const int f = tid & 127, part = tid >> 7;
      float a = 0.f;
      const float* wp = Wss1 + (part * 64) * FF + f;
      #pragma unroll 8
      for (int kk = 0; kk < 64; ++kk) a += as_l[part * 64 + kk] * wp[kk * FF];
      const float* vp = Wvs1 + (part * 32) * FF + f;
      #pragma unroll 8
      for (int vv = 0; vv < 32; ++vv) a += inv_l[part * 32 + vv] * vp[vv * FF];
      red[part * 128 + f] = a;
    }
    __syncthreads();

    if (tid < FF)
      hsn[tid] = silu_f(hs[n * FF + tid] + red[tid] + red[128 + tid]);
    if (tid < 192) {
      const int w = tid / 3, d = tid - w * 3;
      float a = 0.f;
      #pragma unroll 8
      for (int v = 0; v < VV; ++v) a += av_l[v * 3 + d] * Wvv1[v * VV + w];
      hv_l[tid] = hv[n * 192 + tid] + a;
    }
    __syncthreads();

    // readout
    {
      const int f = tid & 127, part = tid >> 7;
      float a = 0.f;
      const float* wp = Wro_s1 + (part * 64) * FF + f;
      #pragma unroll 8
      for (int kk = 0; kk < 64; ++kk) a += hsn[part * 64 + kk] * wp[kk * FF];
      red[part * 128 + f] = a;
    }
    __syncthreads();
    if (tid < FF) t1[tid] = silu_f(red[tid] + red[128 + tid]);
    if (tid < 192) {
      const int w = tid / 3, d = tid - w * 3;
      float a = 0.f;
      #pragma unroll 8
      for (int v = 0; v < VV; ++v) a += hv_l[v * 3 + d] * Wro_v1[v * VV + w];
      tv1[tid] = a;
    }
    __syncthreads();

    if (tid < 128) {
      const int o = tid & 63, part = tid >> 6;
      float a = 0.f;
      const float* wp = Wro_s2 + (part * 64) * 64 + o;
      #pragma unroll 8
      for (int f = 0; f < 64; ++f) a += t1[part * 64 + f] * wp[f * 64];
      red[tid] = a;
    }
    if (tid >= 160) {
      const int j = tid - 160;          // 0..95
      const int w2 = j / 3, d = j - w2 * 3;
      float a = 0.f;
      #pragma unroll 8
      for (int wv = 0; wv < VV; ++wv) a += tv1[wv * 3 + d] * Wro_v2[wv * 32 + w2];
      out[n * 160 + 64 + j] = a;
    }
    __syncthreads();
    if (tid < 64) out[n * 160 + tid] = red[tid] + red[64 + tid];
  }
}

// ---------------------------------------------------------------------------
extern "C" void kernel_launch(void* const* d_in, const int* in_sizes, int n_in,
                              void* d_out, int out_size, void* d_ws, size_t ws_size,
                              hipStream_t stream) {
  const float* x      = (const float*)d_in[0];
  const float* embed  = (const float*)d_in[3];
  const float* Wr1    = (const float*)d_in[4];   // [2][1][16]
  const float* Wr2s   = (const float*)d_in[5];   // [2][16][128]
  const float* Wr2v   = (const float*)d_in[6];   // [2][16][64]
  const float* Wsv    = (const float*)d_in[7];   // [2][128][64]
  const float* Wss    = (const float*)d_in[8];   // [2][128][128]
  const float* Wvs    = (const float*)d_in[9];   // [2][64][128]
  const float* Wvv    = (const float*)d_in[10];  // [2][64][64]
  const float* Wro_s1 = (const float*)d_in[11];
  const float* Wro_s2 = (const float*)d_in[12];
  const float* Wro_v1 = (const float*)d_in[13];
  const float* Wro_v2 = (const float*)d_in[14];

  unsigned* flags   = (unsigned*)d_ws;                   // 768 * 128 B
  unsigned* release = flags + GRID * FLAG_STRIDE;        // offset 98304 B
  float* hs  = (float*)((char*)d_ws + 98816);            // 768*128 f32
  float* hsv = hs + NN * FF;                             // 768*64  f32
  float* hv  = hsv + NN * VV;                            // 768*192 f32
  unsigned short* Ps = (unsigned short*)(hv + NN * 192); // 32*768*128 bf16
  unsigned short* Pv = Ps + (size_t)SPLITK * NN * FF;    // 32*768*256 bf16
  unsigned short* Bs = Pv + (size_t)SPLITK * NN * 256;   // 12288*128 bf16
  unsigned short* Bv = Bs + (size_t)12288 * 128;         // 12288*256 bf16
  float* out = (float*)d_out;

  // zero flags + release each launch (captured; 99 KB, trivial)
  hipMemsetAsync(d_ws, 0, 98816, stream);

  mega_kernel<<<GRID, 256, 0, stream>>>(
      x, embed, Wr1, Wr2s, Wr2v, Wsv, Wss, Wvs, Wvv,
      Wro_s1, Wro_s2, Wro_v1, Wro_v2,
      hs, hsv, hv, Ps, Pv, Bs, Bv, flags, release, out);
}

// Round 17
// 54.750 us; speedup vs baseline: 12.6524x; 12.6524x over previous
//
#include <hip/hip_runtime.h>
#include <hip/hip_bf16.h>
#include <math.h>

#define NN 768
#define FF 128
#define VV 64
#define RH 16
#define SPLITK 24
#define SEND_PER_KC 32          // 768 / SPLITK
#define NITER 4                 // SEND_PER_KC / 8 senders per iter
#define KSTEPS 384              // 12288 / 32
#define NT_S 8                  // scalar n-tiles (128/16)
#define NT_V 16                 // vector n-tiles (256/16)
#define MB_N 24                 // M-blocks (768/32)

typedef __attribute__((ext_vector_type(8))) short bf16x8_t;
typedef __attribute__((ext_vector_type(4))) float f32x4;

__device__ __forceinline__ float silu_f(float a) {
  return a * __builtin_amdgcn_rcpf(1.0f + __expf(-a));
}

__device__ __forceinline__ short f2bf(float f) {
  __hip_bfloat16 h = __float2bfloat16(f);  // RNE; pairs into v_cvt_pk_bf16_f32
  return __builtin_bit_cast(short, h);
}

__device__ __forceinline__ float bf2f(unsigned short v) {
  return __builtin_bit_cast(float, (unsigned)v << 16);
}

// ---------------------------------------------------------------------------
// Layer-0 fused kernel v3 (R14 + B-emission): register-resident moments +
// node update + DIRECT B-fragment emission for layer 1 (prep kernel fused).
// Block s owns sender s: at the end it holds hs[s] (hsn) and hsv[s] in LDS,
// and emits the lanes 32*(s&1)..+31 slice of every B fragment row for
// kstep = s>>1 (disjoint across blocks, complete coverage; layout formula
// identical to the verified prep kernel).
// ---------------------------------------------------------------------------
__global__ __launch_bounds__(256) void layer0_kernel(
    const float* __restrict__ x,
    const float* __restrict__ Wr1,    // [16] layer-0
    const float* __restrict__ Wr2s,   // [2][16][128] (both layers)
    const float* __restrict__ Wr2v,   // [2][16][64]
    const float* __restrict__ embed,  // [128]
    const float* __restrict__ Wsv0,   // [128][64] layer-0
    const float* __restrict__ Wss,    // [128][128] layer-0
    const float* __restrict__ Wvs,    // [64][128]  layer-0
    const float* __restrict__ Wvv,    // [64][64]   layer-0
    const float* __restrict__ Wsv1,   // [128][64]  layer-1 (for hsv)
    float* __restrict__ hs,
    float* __restrict__ hv,
    unsigned short* __restrict__ Bs,  // [384*8][64][8] bf16
    unsigned short* __restrict__ Bv)  // [384*16][64][8] bf16
{
  __shared__ float accT[256 * 33];    // 33.8 KB transpose-reduce scratch
  __shared__ float red8[8][32];
  __shared__ float fin[64];
  __shared__ float cvs[64];
  __shared__ float as_l[FF];
  __shared__ float av_l[192];
  __shared__ float inv_l[VV];
  __shared__ float hsn[FF];
  __shared__ float hsv_l[VV];
  __shared__ float redn[256];

  const int r   = blockIdx.x;
  const int tid = threadIdx.x;

  // c[v] = embed @ Wsv0
  if (tid < 64) {
    float a = 0.f;
    #pragma unroll 8
    for (int f = 0; f < FF; ++f) a += embed[f] * Wsv0[f * VV + tid];
    cvs[tid] = a;
  }

  float wr1[RH];
  #pragma unroll
  for (int hh = 0; hh < RH; ++hh) wr1[hh] = Wr1[hh];

  const float xr0 = x[r * 3 + 0], xr1 = x[r * 3 + 1], xr2 = x[r * 3 + 2];

  float acc[64];
  #pragma unroll
  for (int i = 0; i < 64; ++i) acc[i] = 0.f;

  // ---- main loop: 3 senders per thread, all in registers ----
  #pragma unroll
  for (int ss = 0; ss < 3; ++ss) {
    const int s = tid + ss * 256;
    const float vx = x[s * 3 + 0] - xr0;
    const float vy = x[s * 3 + 1] - xr1;
    const float vz = x[s * 3 + 2] - xr2;
    const float d  = __builtin_amdgcn_sqrtf(vx * vx + vy * vy + vz * vz);
    const float iv = __builtin_amdgcn_rcpf(d + 1e-8f);
    const float ux = vx * iv, uy = vy * iv, uz = vz * iv;
    #pragma unroll
    for (int h = 0; h < RH; ++h) {
      const float rf = silu_f(d * wr1[h]);
      acc[h * 4 + 0] += rf;
      acc[h * 4 + 1] += rf * ux;
      acc[h * 4 + 2] += rf * uy;
      acc[h * 4 + 3] += rf * uz;
    }
  }

  // ---- transpose-reduce: round A (j 0..31), round B (j 32..63) ----
  {
    #pragma unroll
    for (int i = 0; i < 32; ++i) accT[tid * 33 + i] = acc[i];
    __syncthreads();
    {
      const int j2 = tid & 31, q2 = tid >> 5;
      float a0 = 0.f, a1 = 0.f;
      #pragma unroll 8
      for (int rr = 0; rr < 32; rr += 2) {
        a0 += accT[(q2 * 32 + rr) * 33 + j2];
        a1 += accT[(q2 * 32 + rr + 1) * 33 + j2];
      }
      red8[q2][j2] = a0 + a1;
    }
    __syncthreads();
    if (tid < 32) {
      float a = 0.f;
      #pragma unroll
      for (int g = 0; g < 8; ++g) a += red8[g][tid];
      fin[tid] = a;
    }
    __syncthreads();

    #pragma unroll
    for (int i = 0; i < 32; ++i) accT[tid * 33 + i] = acc[32 + i];
    __syncthreads();
    {
      const int j2 = tid & 31, q2 = tid >> 5;
      float a0 = 0.f, a1 = 0.f;
      #pragma unroll 8
      for (int rr = 0; rr < 32; rr += 2) {
        a0 += accT[(q2 * 32 + rr) * 33 + j2];
        a1 += accT[(q2 * 32 + rr + 1) * 33 + j2];
      }
      red8[q2][j2] = a0 + a1;
    }
    __syncthreads();
    if (tid < 32) {
      float a = 0.f;
      #pragma unroll
      for (int g = 0; g < 8; ++g) a += red8[g][tid];
      fin[32 + tid] = a;
    }
    __syncthreads();
  }

  // ---- node tail: agg -> hs/hv/hsv ----
  if (tid < FF) {
    float a = 0.f;
    #pragma unroll
    for (int hh = 0; hh < RH; ++hh) a += fin[hh * 4] * Wr2s[hh * FF + tid];
    as_l[tid] = a * embed[tid] * (1.0f / 64.0f);
  }
  if (tid < 192) {
    const int v = tid / 3, d = tid - v * 3;
    float a = 0.f;
    #pragma unroll
    for (int hh = 0; hh < RH; ++hh) a += fin[hh * 4 + 1 + d] * Wr2v[hh * VV + v];
    av_l[tid] = a * cvs[v] * (1.0f / 64.0f);
  }
  __syncthreads();

  if (tid < VV) {
    const float a0 = av_l[tid * 3 + 0], a1 = av_l[tid * 3 + 1], a2 = av_l[tid * 3 + 2];
    inv_l[tid] = a0 * a0 + a1 * a1 + a2 * a2;
  }
  __syncthreads();

  // hs partials: 2-way K split over 256 threads
  {
    const int f = tid & 127, part = tid >> 7;   // 0/1
    float a = 0.f;
    const float* wp = Wss + (part * 64) * FF + f;
    #pragma unroll 8
    for (int kk = 0; kk < 64; ++kk) a += as_l[part * 64 + kk] * wp[kk * FF];
    const float* vp = Wvs + (part * 32) * FF + f;
    #pragma unroll 8
    for (int vv = 0; vv < 32; ++vv) a += inv_l[part * 32 + vv] * vp[vv * FF];
    redn[part * 128 + f] = a;
  }
  __syncthreads();

  if (tid < FF) {
    const float hnew = silu_f(embed[tid] + redn[tid] + redn[128 + tid]);
    hs[(size_t)r * FF + tid] = hnew;
    hsn[tid] = hnew;
  }
  // hv = av @ Wvv (hv_prev = 0)
  if (tid < 192) {
    const int w = tid / 3, d = tid - w * 3;
    float a = 0.f;
    #pragma unroll 8
    for (int v = 0; v < VV; ++v) a += av_l[v * 3 + d] * Wvv[v * VV + w];
    hv[(size_t)r * 192 + tid] = a;
  }
  __syncthreads();

  // hsv = hsn @ Wsv1 : 4-way split
  {
    const int v = tid & 63, part = tid >> 6;   // 0..3
    float a = 0.f;
    const float* wp = Wsv1 + (part * 32) * VV + v;
    #pragma unroll 8
    for (int f = 0; f < 32; ++f) a += hsn[part * 32 + f] * wp[f * VV];
    redn[tid] = a;
  }
  __syncthreads();
  if (tid < VV)
    hsv_l[tid] = redn[tid] + redn[64 + tid] + redn[128 + tid] + redn[192 + tid];
  __syncthreads();

  // ---- fused B emission for layer 1 (replaces prep kernel) ----
  // this block = sender s = r; kstep = s>>1; lanes 32*(s&1) .. +31.
  {
    const float* W2s = Wr2s + RH * FF;   // layer-1 slices
    const float* W2v = Wr2v + RH * VV;
    const int s     = r;
    const int kstep = s >> 1;
    const int lbase = (s & 1) << 5;
    const float xs0 = x[s * 3 + 0], xs1 = x[s * 3 + 1], xs2 = x[s * 3 + 2];

    #pragma unroll
    for (int k = 0; k < 3; ++k) {
      const int item  = tid + k * 256;   // 0..767
      const int ntile = item >> 5;       // 0..23
      const int li    = item & 31;
      const int lane  = lbase + li;
      const int hb    = ((li >> 4) & 1) * 8;

      bf16x8_t o;
      if (ntile < NT_S) {
        const int f = ntile * 16 + (li & 15);
        const float hf = hsn[f] * 0.015625f;
        #pragma unroll
        for (int e = 0; e < 8; ++e)
          o[e] = f2bf(hf * W2s[(hb + e) * FF + f]);
        *(bf16x8_t*)&Bs[((size_t)(kstep * NT_S + ntile) * 64 + lane) * 8] = o;
      } else {
        const int nt2 = ntile - NT_S;
        const int n   = nt2 * 16 + (li & 15);
        int v; float scale;
        if (n < 192) {
          const int dd = n >> 6; v = n & 63;
          const float xd = (dd == 0) ? xs0 : ((dd == 1) ? xs1 : xs2);
          scale = xd * hsv_l[v] * 0.015625f;
        } else {
          v = n - 192; scale = hsv_l[v] * 0.015625f;
        }
        #pragma unroll
        for (int e = 0; e < 8; ++e)
          o[e] = f2bf(scale * W2v[(hb + e) * VV + v]);
        *(bf16x8_t*)&Bv[((size_t)(kstep * NT_V + nt2) * 64 + lane) * 8] = o;
      }
    }
  }
}

// ---------------------------------------------------------------------------
// edge GEMM v7 (R14 verbatim, bf16 partial output): M=32/block, 4 waves,
// grid = 24 mb x 24 kc = 576. silu chain ONCE per (r,s); A_lds + G_lds.
// ---------------------------------------------------------------------------
__global__ __launch_bounds__(256) void edge_gemm(
    const float* __restrict__ x,
    const unsigned short* __restrict__ Bs,
    const unsigned short* __restrict__ Bv,
    const float* __restrict__ Wr1,    // [16] layer-1 slice
    unsigned short* __restrict__ Ps,  // [SPLITK][768][128] bf16
    unsigned short* __restrict__ Pv)  // [SPLITK][768][256] bf16
{
  __shared__ unsigned short A_lds[4 * 2 * 64 * 8];  // 8 KB scalar A
  __shared__ unsigned short G_lds[4 * 2 * 64 * 8];  // 8 KB vector A (rf*iv)

  // bijective XCD swizzle: 576 = 8 * 72; xcd owns kc in [3*xcd, 3*xcd+2]
  const int wg = ((blockIdx.x & 7) * 72) + (blockIdx.x >> 3);
  const int kc = wg / MB_N;
  const int mb = wg - kc * MB_N;

  const int tid  = threadIdx.x;
  const int lane = tid & 63;
  const int w    = tid >> 6;

  float wr1[RH];
  #pragma unroll
  for (int h = 0; h < RH; ++h) wr1[h] = Wr1[h];

  const int r_local = tid & 31;
  const int s_ii    = tid >> 5;        // 0..7
  const int r = mb * 32 + r_local;
  const int mt_w  = r_local >> 4;
  const int ks_w  = s_ii >> 1;
  const int lane0 = (r_local & 15) + ((s_ii & 1) << 5);

  const float xr0 = x[r * 3 + 0], xr1 = x[r * 3 + 1], xr2 = x[r * 3 + 2];
  float sx[NITER], sy[NITER], sz[NITER];
  #pragma unroll
  for (int it = 0; it < NITER; ++it) {
    const int s = kc * SEND_PER_KC + it * 8 + s_ii;
    sx[it] = x[s * 3 + 0]; sy[it] = x[s * 3 + 1]; sz[it] = x[s * 3 + 2];
  }

  f32x4 accS[4], accV[8];
  #pragma unroll
  for (int i = 0; i < 4; ++i) accS[i] = (f32x4){0.f, 0.f, 0.f, 0.f};
  #pragma unroll
  for (int i = 0; i < 8; ++i) accV[i] = (f32x4){0.f, 0.f, 0.f, 0.f};

  for (int it = 0; it < NITER; ++it) {
    // ---- A generation: silu chain ONCE, two LDS images ----
    {
      const float vx = sx[it] - xr0;
      const float vy = sy[it] - xr1;
      const float vz = sz[it] - xr2;
      const float dd = __builtin_amdgcn_sqrtf(vx * vx + vy * vy + vz * vz);
      const float iv = __builtin_amdgcn_rcpf(dd + 1e-8f);
      float sv[RH];
      #pragma unroll
      for (int h = 0; h < RH; ++h) sv[h] = silu_f(dd * wr1[h]);
      bf16x8_t o0, o1, g0, g1;
      #pragma unroll
      for (int h = 0; h < 8; ++h) {
        o0[h] = f2bf(sv[h]);
        o1[h] = f2bf(sv[h + 8]);
        g0[h] = f2bf(sv[h] * iv);
        g1[h] = f2bf(sv[h + 8] * iv);
      }
      const int off0 = ((ks_w * 2 + mt_w) * 64 + lane0) * 8;
      *(bf16x8_t*)&A_lds[off0]       = o0;
      *(bf16x8_t*)&A_lds[off0 + 128] = o1;   // +16 lanes * 8
      *(bf16x8_t*)&G_lds[off0]       = g0;
      *(bf16x8_t*)&G_lds[off0 + 128] = g1;
    }
    __syncthreads();

    // ---- MFMA: scalar (2 nt) + vector (4 nt) per wave ----
    const int kgb = kc * (SEND_PER_KC / 2) + it * 4;
    #pragma unroll
    for (int ks = 0; ks < 4; ++ks) {
      const bf16x8_t b0 =
          *(const bf16x8_t*)&Bs[((size_t)((kgb + ks) * NT_S + 2 * w) * 64 + lane) * 8];
      const bf16x8_t b1 =
          *(const bf16x8_t*)&Bs[((size_t)((kgb + ks) * NT_S + 2 * w + 1) * 64 + lane) * 8];
      bf16x8_t bv[4];
      #pragma unroll
      for (int j = 0; j < 4; ++j)
        bv[j] = *(const bf16x8_t*)&Bv[((size_t)((kgb + ks) * NT_V + 4 * w + j) * 64 + lane) * 8];
      #pragma unroll
      for (int mt = 0; mt < 2; ++mt) {
        const int aoff = ((ks * 2 + mt) * 64 + lane) * 8;
        const bf16x8_t a  = *(const bf16x8_t*)&A_lds[aoff];
        const bf16x8_t ag = *(const bf16x8_t*)&G_lds[aoff];
        accS[mt * 2 + 0] = __builtin_amdgcn_mfma_f32_16x16x32_bf16(a, b0, accS[mt * 2 + 0], 0, 0, 0);
        accS[mt * 2 + 1] = __builtin_amdgcn_mfma_f32_16x16x32_bf16(a, b1, accS[mt * 2 + 1], 0, 0, 0);
        #pragma unroll
        for (int j = 0; j < 4; ++j)
          accV[mt * 4 + j] = __builtin_amdgcn_mfma_f32_16x16x32_bf16(ag, bv[j], accV[mt * 4 + j], 0, 0, 0);
      }
    }
    __syncthreads();
  }

  // ---- epilogue: write bf16 partials (each element written exactly once) ----
  const int rowq = (lane >> 4) << 2;
  #pragma unroll
  for (int j = 0; j < 2; ++j) {
    const int col = (2 * w + j) * 16 + (lane & 15);
    #pragma unroll
    for (int mt = 0; mt < 2; ++mt) {
      #pragma unroll
      for (int reg = 0; reg < 4; ++reg) {
        const int row = mb * 32 + mt * 16 + rowq + reg;
        Ps[((size_t)kc * NN + row) * FF + col] =
            (unsigned short)f2bf(accS[mt * 2 + j][reg]);
      }
    }
  }
  #pragma unroll
  for (int j = 0; j < 4; ++j) {
    const int col = (4 * w + j) * 16 + (lane & 15);
    #pragma unroll
    for (int mt = 0; mt < 2; ++mt) {
      #pragma unroll
      for (int reg = 0; reg < 4; ++reg) {
        const int row = mb * 32 + mt * 16 + rowq + reg;
        Pv[((size_t)kc * NN + row) * 256 + col] =
            (unsigned short)f2bf(accV[mt * 4 + j][reg]);
      }
    }
  }
}

// ---------------------------------------------------------------------------
// final kernel (R14 verbatim): node1 (bf16 partial reduce) + readout fused.
// ---------------------------------------------------------------------------
__global__ __launch_bounds__(512) void final_kernel(
    const unsigned short* __restrict__ Ps,  // [SPLITK][768][128] bf16
    const unsigned short* __restrict__ Pv,  // [SPLITK][768][256] bf16
    const float* __restrict__ x,
    const float* __restrict__ hs,       // layer-0 output
    const float* __restrict__ hv,       // layer-0 output
    const float* __restrict__ Wss,      // layer-1
    const float* __restrict__ Wvs,      // layer-1
    const float* __restrict__ Wvv,      // layer-1
    const float* __restrict__ Wro_s1,
    const float* __restrict__ Wro_s2,
    const float* __restrict__ Wro_v1,
    const float* __restrict__ Wro_v2,
    float* __restrict__ out)
{
  __shared__ float as_l[FF];
  __shared__ float pvs_l[256];
  __shared__ float av_l[192];
  __shared__ float inv_l[VV];
  __shared__ float hsn[FF];
  __shared__ float hv_l[192];
  __shared__ float red[512];
  __shared__ float red2[384];
  __shared__ float t1[FF];
  __shared__ float tv1[192];
  const int n = blockIdx.x, t = threadIdx.x;

  // fused splitK reduce (bf16 loads)
  if (t < FF) {
    float a = 0.f;
    #pragma unroll
    for (int kc = 0; kc < SPLITK; ++kc)
      a += bf2f(Ps[((size_t)kc * NN + n) * FF + t]);
    as_l[t] = a;
  } else if (t < 384) {
    const int cc = t - 128;
    float a = 0.f;
    #pragma unroll
    for (int kc = 0; kc < SPLITK; ++kc)
      a += bf2f(Pv[((size_t)kc * NN + n) * 256 + cc]);
    pvs_l[cc] = a;
  }
  __syncthreads();

  if (t < VV) {
    const float base = pvs_l[192 + t];
    const float a0 = pvs_l[t]       - x[n * 3 + 0] * base;
    const float a1 = pvs_l[64 + t]  - x[n * 3 + 1] * base;
    const float a2 = pvs_l[128 + t] - x[n * 3 + 2] * base;
    av_l[t * 3 + 0] = a0; av_l[t * 3 + 1] = a1; av_l[t * 3 + 2] = a2;
    inv_l[t] = a0 * a0 + a1 * a1 + a2 * a2;
  }
  __syncthreads();

  // hs partials: 4-way split over K
  {
    const int f = t & 127, part = t >> 7;
    float acc = 0.f;
    const float* wp = Wss + (part * 32) * FF + f;
    #pragma unroll 8
    for (int kk = 0; kk < 32; ++kk) acc += as_l[part * 32 + kk] * wp[kk * FF];
    const float* vp = Wvs + (part * 16) * FF + f;
    #pragma unroll 8
    for (int vv = 0; vv < 16; ++vv) acc += inv_l[part * 16 + vv] * vp[vv * FF];
    red[part * 128 + f] = acc;
  }
  __syncthreads();

  if (t < FF) {
    hsn[t] = silu_f(hs[n * FF + t] + red[t] + red[128 + t] + red[256 + t] + red[384 + t]);
  }
  if (t < 384) {
    const int part = t / 192, j = t - part * 192;
    const int wv = j / 3, d = j - wv * 3;
    float acc = 0.f;
    const float* vp = Wvv + (part * 32) * VV + wv;
    #pragma unroll 8
    for (int v = 0; v < 32; ++v) acc += av_l[(part * 32 + v) * 3 + d] * vp[v * VV];
    red2[part * 192 + j] = acc;
  }
  __syncthreads();

  if (t < 192) hv_l[t] = hv[n * 192 + t] + red2[t] + red2[192 + t];
  __syncthreads();

  // ---- readout, inputs hsn / hv_l ----
  {
    const int f = t & 127, part = t >> 7;
    float acc = 0.f;
    const float* wp = Wro_s1 + (part * 32) * FF + f;
    #pragma unroll 8
    for (int kk = 0; kk < 32; ++kk) acc += hsn[part * 32 + kk] * wp[kk * FF];
    red[part * 128 + f] = acc;
  }
  __syncthreads();
  if (t < FF) t1[t] = silu_f(red[t] + red[128 + t] + red[256 + t] + red[384 + t]);
  if (t < 384) {
    const int part = t / 192, j = t - part * 192;
    const int wv = j / 3, d = j - wv * 3;
    float acc = 0.f;
    const float* vp = Wro_v1 + (part * 32) * VV + wv;
    #pragma unroll 8
    for (int v = 0; v < 32; ++v) acc += hv_l[(part * 32 + v) * 3 + d] * vp[v * VV];
    red2[part * 192 + j] = acc;
  }
  __syncthreads();
  if (t < 192) tv1[t] = red2[t] + red2[192 + t];
  if (t < 256) {
    const int o = t & 63, part = t >> 6;
    float acc = 0.f;
    const float* wp = Wro_s2 + (part * 32) * 64 + o;
    #pragma unroll 8
    for (int f = 0; f < 32; ++f) acc += t1[part * 32 + f] * wp[f * 64];
    red[t] = acc;
  }
  __syncthreads();
  if (t < 64) out[n * 160 + t] = red[t] + red[64 + t] + red[128 + t] + red[192 + t];
  if (t < 192) {
    const int part = t / 96, j = t - part * 96;
    const int w2 = j / 3, d = j - w2 * 3;
    float acc = 0.f;
    const float* vp = Wro_v2 + (part * 32) * 32 + w2;
    #pragma unroll 8
    for (int wv = 0; wv < 32; ++wv) acc += tv1[(part * 32 + wv) * 3 + d] * vp[wv * 32];
    red2[part * 96 + j] = acc;
  }
  __syncthreads();
  if (t < 96) out[n * 160 + 64 + t] = red2[t] + red2[96 + t];
}

// ---------------------------------------------------------------------------
extern "C" void kernel_launch(void* const* d_in, const int* in_sizes, int n_in,
                              void* d_out, int out_size, void* d_ws, size_t ws_size,
                              hipStream_t stream) {
  const float* x      = (const float*)d_in[0];
  const float* embed  = (const float*)d_in[3];
  const float* Wr1    = (const float*)d_in[4];   // [2][1][16]
  const float* Wr2s   = (const float*)d_in[5];   // [2][16][128]
  const float* Wr2v   = (const float*)d_in[6];   // [2][16][64]
  const float* Wsv    = (const float*)d_in[7];   // [2][128][64]
  const float* Wss    = (const float*)d_in[8];   // [2][128][128]
  const float* Wvs    = (const float*)d_in[9];   // [2][64][128]
  const float* Wvv    = (const float*)d_in[10];  // [2][64][64]
  const float* Wro_s1 = (const float*)d_in[11];
  const float* Wro_s2 = (const float*)d_in[12];
  const float* Wro_v1 = (const float*)d_in[13];
  const float* Wro_v2 = (const float*)d_in[14];

  float* ws_f = (float*)d_ws;
  float* hs    = ws_f;                      // 768*128 f32
  float* hv    = hs + NN * FF;              // 768*192 f32
  unsigned short* Ps = (unsigned short*)(hv + NN * 192);       // 24*768*128 bf16
  unsigned short* Pv = Ps + (size_t)SPLITK * NN * FF;          // 24*768*256 bf16
  unsigned short* Bs = Pv + (size_t)SPLITK * NN * 256;         // 12288*128 bf16
  unsigned short* Bv = Bs + (size_t)12288 * 128;               // 12288*256 bf16
  float* out = (float*)d_out;

  // layer 0 (closed form, register moments) + node0 + B emission, fused
  layer0_kernel<<<NN, 256, 0, stream>>>(
      x, Wr1, Wr2s, Wr2v, embed, Wsv, Wss, Wvs, Wvv, Wsv + FF * VV,
      hs, hv, Bs, Bv);

  // layer 1: combined-kind MFMA edge GEMM -> node1+readout fused
  edge_gemm<<<MB_N * SPLITK, 256, 0, stream>>>(
      x, Bs, Bv, Wr1 + RH, Ps, Pv);
  final_kernel<<<NN, 512, 0, stream>>>(
      Ps, Pv, x, hs, hv, Wss + FF * FF, Wvs + VV * FF, Wvv + VV * VV,
      Wro_s1, Wro_s2, Wro_v1, Wro_v2, out);
}